// Round 8
// baseline (128.203 us; speedup 1.0000x reference)
//
#include <hip/hip_runtime.h>

#define TOPK 20
#define NITEMS 50000
#define BLOCK 1024
#define NBINS 2048
#define CHUNKS 32
#define STEPS 64                       // NBINS / CHUNKS
#define XMAX 6.0f
#define SCALE (2048.0f / 12.0f)        // bins per score unit; XMAX*SCALE = 1024
#define DELTA (12.0f / 2048.0f)
#define RSCALE (12.0f / 2048.0f / 4096.0f)   // fixed-point residual -> score units
#define KSTRIDE 0.8290291182f          // exp(-CHUNKS*DELTA) = exp(-0.1875)
#define REPEAT 4                       // DIAGNOSTIC: x4 idempotent repeat to surface counters
#define PFD 4                          // prefetch depth

// SmoothRank NDCG via packed per-row histogram + first-order residual
// correction (math validated rounds 4-7, absmax 4.9e-4 vs 3.65e-3 threshold).
// Round-8 = instrumented: whole pipeline repeated REPEAT times with identical
// output (no state carries across passes) so the warm kernel exceeds the
// 42us harness fills and surfaces in rocprof top-5.  Also carries the two
// model-endorsed fixes: 4-deep Phase-A prefetch (break the ~900cyc HBM
// latency serialization at 1-deep) and a wave-parallel NDCG epilogue.
__global__ __launch_bounds__(BLOCK) void smoothdcg_kernel(
    const float* __restrict__ scores_top,  // [B][TOPK]
    const float* __restrict__ scores,      // [B][NITEMS]
    const float* __restrict__ labels,      // [B][TOPK]
    float* __restrict__ out)               // [B][TOPK]
{
    const int b   = blockIdx.x;
    const int tid = threadIdx.x;

    __shared__ unsigned int hist[NBINS];   // 8 KB packed count|residual
    __shared__ float s_t[TOPK];
    __shared__ float s_rank[TOPK];

    if (tid < TOPK) s_t[tid] = scores_top[b * TOPK + tid];

    const float4* row = (const float4*)(scores + (size_t)b * NITEMS);
    const int n4 = NITEMS / 4;  // 12500

    for (int r = 0; r < REPEAT; ++r) {
#pragma unroll
        for (int i = tid; i < NBINS; i += BLOCK) hist[i] = 0u;
        __syncthreads();

        // ---- Phase A: packed histogram, 4-deep rolling prefetch ----
        float4 v[PFD];
#pragma unroll
        for (int d = 0; d < PFD; ++d) {
            v[d] = make_float4(0.f, 0.f, 0.f, 0.f);
            if (tid + d * BLOCK < n4) v[d] = row[tid + d * BLOCK];
        }
        for (int i = tid; i < n4; i += BLOCK) {
            float4 cur = v[0];
#pragma unroll
            for (int d = 0; d < PFD - 1; ++d) v[d] = v[d + 1];
            const int inx = i + PFD * BLOCK;
            v[PFD - 1] = make_float4(0.f, 0.f, 0.f, 0.f);
            if (inx < n4) v[PFD - 1] = row[inx];

            float s4[4] = {cur.x, cur.y, cur.z, cur.w};
#pragma unroll
            for (int k = 0; k < 4; ++k) {
                float s = fminf(fmaxf(s4[k], -5.9999f), 5.9999f);
                float f = fmaf(s, SCALE, 1024.0f);        // in (0, 2048)
                int idx  = (int)f;                        // trunc == floor
                float ff = f - (float)idx;                // frac in [0,1)
                unsigned int contrib = (unsigned int)fmaf(ff, 4096.0f, 1048576.0f);
                atomicAdd(&hist[idx], contrib);           // native ds_add_u32
            }
        }
        __syncthreads();

        // ---- Phase B: rank_j = sum_m [w*sig + R*sig'] over the histogram ----
        if (tid < TOPK * CHUNKS) {  // 640 active
            const int j  = tid >> 5;
            const int qc = tid & 31;
            const float t  = s_t[j];
            const float x0 = fmaf((float)qc + 0.5f, DELTA, -XMAX);
            float u = __expf(t - x0);
            float accW = 0.0f, accQ = 0.0f;
            int m = qc;
#pragma unroll 8
            for (int p = 0; p < STEPS; ++p) {
                unsigned int word = hist[m];
                unsigned int w  = word >> 20;
                int Q = (int)(word & 0xFFFFFu) - (int)(w << 11);
                float sg  = __builtin_amdgcn_rcpf(1.0f + u);
                float sgp = fmaf(-sg, sg, sg);
                accW = fmaf((float)w, sg, accW);
                accQ = fmaf((float)Q, sgp, accQ);
                u *= KSTRIDE;
                m += CHUNKS;
            }
            float acc = fmaf(accQ, RSCALE, accW);
#pragma unroll
            for (int off = 16; off >= 1; off >>= 1)
                acc += __shfl_down(acc, off, 64);
            if (qc == 0) s_rank[j] = acc;
        }
        __syncthreads();

        // ---- Epilogue: wave-parallel NDCG (wave 0 only) ----
        if (tid < 64) {
            const int lane = tid;
            float p = 0.0f, lab = 0.0f;
            if (lane < TOPK) {
                p   = s_rank[lane];
                lab = labels[b * TOPK + lane];
            }
            float rank = p + 0.5f;
            float d  = __log2f(rank + 1.0f);
            float dg = (lane < TOPK) ? lab / d : 0.0f;
#pragma unroll
            for (int off = 1; off < 32; off <<= 1) {
                float tmp = __shfl_up(dg, off, 64);
                if (lane >= off) dg += tmp;
            }
            unsigned long long mk = __ballot(lab > 0.5f);
            int ksum = __popcll(mk & 0xFFFFFull);
            float rr = (lane < TOPK) ? 1.0f / __log2f((float)lane + 2.0f) : 0.0f;
#pragma unroll
            for (int off = 1; off < 32; off <<= 1) {
                float tmp = __shfl_up(rr, off, 64);
                if (lane >= off) rr += tmp;
            }
            if (lane < TOPK) {
                int kc  = (ksum < lane + 1) ? ksum : (lane + 1);
                int idx = kc - 1;
                if (idx < 0) idx += TOPK;   // JAX negative-index wrap (k_sum==0)
                float iv = __shfl(rr, idx, 64);
                out[b * TOPK + lane] = dg / iv;
            }
        }
        __syncthreads();   // order epilogue reads before next pass overwrites s_rank
    }
}

extern "C" void kernel_launch(void* const* d_in, const int* in_sizes, int n_in,
                              void* d_out, int out_size, void* d_ws, size_t ws_size,
                              hipStream_t stream) {
    const float* scores_top = (const float*)d_in[0];
    const float* scores     = (const float*)d_in[1];
    const float* labels     = (const float*)d_in[2];
    float* out              = (float*)d_out;

    const int B = in_sizes[0] / TOPK;  // 256
    smoothdcg_kernel<<<dim3(B), dim3(BLOCK), 0, stream>>>(scores_top, scores, labels, out);
}

// Round 9
// 94.009 us; speedup vs baseline: 1.3637x; 1.3637x over previous
//
#include <hip/hip_runtime.h>

#define TOPK 20
#define NITEMS 50000
#define BLOCK 1024
#define NBINS 2048
#define CHUNKS 32
#define STEPS 64                       // NBINS / CHUNKS
#define XMAX 6.0f
#define SCALE (2048.0f / 12.0f)        // bins per score unit; XMAX*SCALE = 1024
#define DELTA (12.0f / 2048.0f)
#define RSCALE (12.0f / 2048.0f / 4096.0f)   // fixed-point residual -> score units
#define KSTRIDE 0.8290291182f          // exp(-CHUNKS*DELTA) = exp(-0.1875)
#define FULL 12                        // 12*1024 guard-free float4 iterations
#define FULLN (FULL * BLOCK)           // 12288
#define TAIL (NITEMS / 4 - FULLN)      // 212

// SmoothRank NDCG via packed per-row histogram + first-order residual
// correction (validated rounds 4-8: absmax 4.9e-4 vs 3.65e-3 threshold).
// Round-9 (from round-8 diagnostic counters: Phase A is memory-stream-bound,
// ~5-6us/CU; atomics ~1.6us; VALU not saturated):
//   * all 12 guard-free loads issued BEFORE the hist-init barrier -> HBM
//     latency overlaps LDS init, ~192KB/CU in flight, zero rotation/guard VALU
//   * fused fixed-point binning: 6 VALU/item (med3 clamp, 1 fma, cvt,
//     shift/and/or), one packed ds_add_u32/item
//   * labels preloaded into wave-0 registers (no cold load in epilogue)
__global__ __launch_bounds__(BLOCK, 4) void smoothdcg_kernel(
    const float* __restrict__ scores_top,  // [B][TOPK]
    const float* __restrict__ scores,      // [B][NITEMS]
    const float* __restrict__ labels,      // [B][TOPK]
    float* __restrict__ out)               // [B][TOPK]
{
    const int b   = blockIdx.x;
    const int tid = threadIdx.x;

    __shared__ unsigned int hist[NBINS];   // 8 KB packed count|residual
    __shared__ float s_t[TOPK];
    __shared__ float s_rank[TOPK];

    const float4* row = (const float4*)(scores + (size_t)b * NITEMS);

    // ---- issue the whole row's loads up front (overlap with LDS init) ----
    float4 v[FULL];
#pragma unroll
    for (int k = 0; k < FULL; ++k) v[k] = row[tid + (k << 10)];
    float4 vt = make_float4(0.f, 0.f, 0.f, 0.f);
    if (tid < TAIL) vt = row[FULLN + tid];

    float lab = 0.0f;
    if (tid < TOPK) {
        s_t[tid] = scores_top[b * TOPK + tid];
        lab = labels[b * TOPK + tid];   // stays in wave-0 registers for epilogue
    }

#pragma unroll
    for (int i = tid; i < NBINS; i += BLOCK) hist[i] = 0u;
    __syncthreads();

    // ---- Phase A: fused fixed-point binning, one packed ds_add per item ----
    // g = (s+6)*SCALE*4096 ; idx = g>>12 ; lo = g&4095 (frac in Delta/4096 units)
    // packed word: count at bit 20 | lo.  Overflow needs ~512 items in one
    // bin (+36 sigma of the ~117-item hot bin) — safe (validated r6-r8).
#define BIN1(S)                                                              \
    do {                                                                     \
        float sc_ = __builtin_amdgcn_fmed3f((S), -5.9999f, 5.9999f);         \
        float g_  = fmaf(sc_, SCALE * 4096.0f, 4194304.0f);                  \
        int gi_   = (int)g_;                                                 \
        atomicAdd(&hist[gi_ >> 12],                                          \
                  (unsigned int)(1048576 | (gi_ & 4095)));                   \
    } while (0)

#pragma unroll
    for (int k = 0; k < FULL; ++k) {
        BIN1(v[k].x); BIN1(v[k].y); BIN1(v[k].z); BIN1(v[k].w);
    }
    if (tid < TAIL) {
        BIN1(vt.x); BIN1(vt.y); BIN1(vt.z); BIN1(vt.w);
    }
#undef BIN1
    __syncthreads();

    // ---- Phase B: rank_j = sum_m [w_m*sig(x_m-t_j) + R_m*sig'(x_m-t_j)] ----
    // thread (j, qc): j = tid>>5 (aligned 32-lane group), chunk qc = tid&31;
    // scans bins qc, qc+32, ... with geometric recurrence u *= exp(-32*DELTA).
    if (tid < TOPK * CHUNKS) {  // 640 active
        const int j  = tid >> 5;
        const int qc = tid & 31;
        const float t  = s_t[j];
        const float x0 = fmaf((float)qc + 0.5f, DELTA, -XMAX);
        float u = __expf(t - x0);                 // exp(t_j - x_qc)
        float accW = 0.0f, accQ = 0.0f;
        int m = qc;
#pragma unroll 8
        for (int p = 0; p < STEPS; ++p) {
            unsigned int word = hist[m];
            unsigned int w  = word >> 20;
            int Q = (int)(word & 0xFFFFFu) - (int)(w << 11);
            float sg  = __builtin_amdgcn_rcpf(1.0f + u);  // sigmoid(x_m - t)
            float sgp = fmaf(-sg, sg, sg);                // sig*(1-sig)
            accW = fmaf((float)w, sg, accW);
            accQ = fmaf((float)Q, sgp, accQ);
            u *= KSTRIDE;
            m += CHUNKS;
        }
        float acc = fmaf(accQ, RSCALE, accW);
#pragma unroll
        for (int off = 16; off >= 1; off >>= 1)
            acc += __shfl_down(acc, off, 64);     // 32-lane group reduce
        if (qc == 0) s_rank[j] = acc;
    }
    __syncthreads();

    // ---- Epilogue: wave-parallel NDCG (wave 0; validated round 8) ----
    if (tid < 64) {
        const int lane = tid;
        float p = (lane < TOPK) ? s_rank[lane] : 0.0f;
        float rank = p + 0.5f;
        float d  = __log2f(rank + 1.0f);
        float dg = (lane < TOPK) ? lab / d : 0.0f;
#pragma unroll
        for (int off = 1; off < 32; off <<= 1) {
            float tmp = __shfl_up(dg, off, 64);
            if (lane >= off) dg += tmp;
        }
        unsigned long long mk = __ballot(lab > 0.5f);
        int ksum = __popcll(mk & 0xFFFFFull);
        float rr = (lane < TOPK) ? 1.0f / __log2f((float)lane + 2.0f) : 0.0f;
#pragma unroll
        for (int off = 1; off < 32; off <<= 1) {
            float tmp = __shfl_up(rr, off, 64);
            if (lane >= off) rr += tmp;
        }
        if (lane < TOPK) {
            int kc  = (ksum < lane + 1) ? ksum : (lane + 1);
            int idx = kc - 1;
            if (idx < 0) idx += TOPK;   // JAX negative-index wrap (k_sum==0)
            float iv = __shfl(rr, idx, 64);
            out[b * TOPK + lane] = dg / iv;
        }
    }
}

extern "C" void kernel_launch(void* const* d_in, const int* in_sizes, int n_in,
                              void* d_out, int out_size, void* d_ws, size_t ws_size,
                              hipStream_t stream) {
    const float* scores_top = (const float*)d_in[0];
    const float* scores     = (const float*)d_in[1];
    const float* labels     = (const float*)d_in[2];
    float* out              = (float*)d_out;

    const int B = in_sizes[0] / TOPK;  // 256
    smoothdcg_kernel<<<dim3(B), dim3(BLOCK), 0, stream>>>(scores_top, scores, labels, out);
}